// Round 4
// baseline (376.895 us; speedup 1.0000x reference)
//
#include <hip/hip_runtime.h>
#include <hip/hip_bf16.h>
#include <cstdint>
#include <cstddef>

// ---------------------------------------------------------------------------
// SwinWindowTransformLayer: roll+add -> LayerNorm -> MLP(GELU) -> +x
// Round 4: persistent 8-phase GEMM + k-permuted hbuf enabling packed 8B
// epilogue stores, spread (phase-overlapped) gelu epilogue, name-split
// kernels for per-GEMM profiling.
// ---------------------------------------------------------------------------

typedef short bf16x8 __attribute__((ext_vector_type(8)));
typedef float f32x4 __attribute__((ext_vector_type(4)));

#define GLOBAL_AS(p) ((__attribute__((address_space(1))) void*)(uintptr_t)(p))
#define LDS_AS(p)    ((__attribute__((address_space(3))) void*)(p))

template <int I> struct ic { static constexpr int value = I; };

static __device__ __forceinline__ ushort f2bf(float f) {
    uint32_t u = __float_as_uint(f);
    uint32_t r = (u + 0x7FFFu + ((u >> 16) & 1u)) >> 16;
    return (ushort)r;
}

// exact rewrite of tanh-gelu: 0.5v(1+tanh(u)) == v*sigmoid(2u)
static __device__ __forceinline__ float gelu_s(float v) {
    float v2 = v * v;
    float m = fmaf(0.07135481283f, v2, 1.5957691216f);  // 2u = v*(A + B v^2)
    float e = __expf(-v * m);
    return v * __builtin_amdgcn_rcpf(1.0f + e);
}

// roll by (-4,-4) on a 64x64 grid
static __device__ __forceinline__ int rolled_row(int row) {
    int b = row >> 12, n = row & 4095;
    int h = n >> 6, wv = n & 63;
    int n2 = (((h + 4) & 63) << 6) | ((wv + 4) & 63);
    return (b << 12) | n2;
}

#define SBAR() do { __builtin_amdgcn_sched_barrier(0); \
                    __builtin_amdgcn_s_barrier(); \
                    __builtin_amdgcn_sched_barrier(0); } while (0)

// ---------------------------------------------------------------------------
__global__ __launch_bounds__(128)
void ln_kernel(const float* __restrict__ in, const float* __restrict__ gamma,
               const float* __restrict__ beta, ushort* __restrict__ normed) {
    const int row = blockIdx.x;
    const int t = threadIdx.x;
    const int row2 = rolled_row(row);

    const float4* p0 = (const float4*)(in + (size_t)row * 512);
    const float4* p1 = (const float4*)(in + (size_t)row2 * 512);
    float4 a = p0[t], c = p1[t];
    float x0 = a.x + c.x, x1 = a.y + c.y, x2 = a.z + c.z, x3 = a.w + c.w;

    float s = x0 + x1 + x2 + x3;
    float sq = x0 * x0 + x1 * x1 + x2 * x2 + x3 * x3;
#pragma unroll
    for (int o = 32; o > 0; o >>= 1) {
        s += __shfl_xor(s, o);
        sq += __shfl_xor(sq, o);
    }
    __shared__ float red[4];
    if ((t & 63) == 0) { red[(t >> 6) * 2] = s; red[(t >> 6) * 2 + 1] = sq; }
    __syncthreads();
    s = red[0] + red[2];
    sq = red[1] + red[3];
    float mu = s * (1.0f / 512.0f);
    float var = sq * (1.0f / 512.0f) - mu * mu;
    float rs = rsqrtf(var + 1e-6f);

    float4 g = ((const float4*)gamma)[t];
    float4 be = ((const float4*)beta)[t];
    ushort4 o4;
    o4.x = f2bf((x0 - mu) * rs * g.x + be.x);
    o4.y = f2bf((x1 - mu) * rs * g.y + be.y);
    o4.z = f2bf((x2 - mu) * rs * g.z + be.z);
    o4.w = f2bf((x3 - mu) * rs * g.w + be.w);
    ((ushort4*)(normed + (size_t)row * 512))[t] = o4;
}

// ---------------------------------------------------------------------------
// transpose + cast fp32 [R][Ccols] -> bf16 [Ccols][R].
// PERM=1: permute the k index (within 64-blocks: nf*16+c -> c*4+nf) to match
// the permuted hbuf layout written by mlp_gemm1's epilogue.
// ---------------------------------------------------------------------------
template <int PERM>
__global__ __launch_bounds__(256)
void transpose_cast(const float* __restrict__ src, ushort* __restrict__ dst,
                    int R, int Ccols) {
    __shared__ float tile[32][33];
    const int bx = blockIdx.x * 32;
    const int by = blockIdx.y * 32;
    const int tx = threadIdx.x, ty = threadIdx.y;
#pragma unroll
    for (int i = 0; i < 32; i += 8)
        tile[ty + i][tx] = src[(size_t)(by + ty + i) * Ccols + bx + tx];
    __syncthreads();
    int k = by + tx;
    int kd = PERM ? ((k & ~63) | ((k & 15) << 2) | ((k >> 4) & 3)) : k;
#pragma unroll
    for (int i = 0; i < 32; i += 8)
        dst[(size_t)(bx + ty + i) * R + kd] = f2bf(tile[tx][ty + i]);
}

// ---------------------------------------------------------------------------
// Persistent 8-phase 256x256 GEMM body (shared by mlp_gemm1 / mlp_gemm2).
// EPI=0: h = bf16(gelu(acc+bias)) stored k-PERMUTED as uint2 (8B) stores;
//        epilogue spread as 8 slices over the next group's phases.
// EPI=1: out = acc + bias + resid[row] + resid[rolled(row)] (f32).
// ---------------------------------------------------------------------------
template <int EPI, int GROUPS, int KT, int LOG2NCB>
__device__ __forceinline__ void gemm8p_body(
        const ushort* __restrict__ A, const ushort* __restrict__ Bt,
        const float* __restrict__ bias, const float* __restrict__ resid,
        ushort* __restrict__ outH, float* __restrict__ outF, int N) {
    constexpr int NT_L = KT / 64;
    constexpr int TT = GROUPS * NT_L;
    constexpr bool SPREAD = (EPI == 0 && GROUPS > 1);
    __shared__ __align__(16) char sm[131072];
    const int t = threadIdx.x;
    const int w = t >> 6, l = t & 63;
    const int wr = w >> 2, wc = w & 3;

    // XCD-aware bijective swizzle (nwg = 256, divisible by 8)
    const int nwg = gridDim.x;
    const int bid = blockIdx.x;
    const int swz = (bid & 7) * (nwg >> 3) + (bid >> 3);
    const int cb = swz & ((1 << LOG2NCB) - 1);
    const int rgrp = swz >> LOG2NCB;
    const int brow0 = rgrp * (GROUPS * 256);
    const int bcol = cb << 8;

    // staging source; k-chunk pre-swizzled (inverse of read XOR)
    const int kksw = (((t & 3) ^ ((t >> 4) & 3)) << 3);
    const size_t aTh = (size_t)(t >> 2) * KT + kksw;
    const size_t bTh = (size_t)(bcol + (t >> 2)) * KT + kksw;
    const ushort* const aPanel = A + (size_t)brow0 * KT;
    char* const dA = (char*)sm + (w << 10);   // wave-uniform dest base
    char* const dB = dA + 65536;

    // fragment ds_read offsets: byte = row*64 + (l>>4)*16, XOR-swizzled
    const int xorv = ((l >> 2) & 3) << 4;
    const int preA = ((((wr << 7) + (l & 15)) << 6) + ((l >> 4) << 4)) ^ xorv;
    const int preB = 65536 + (((((wc << 6) + (l & 15)) << 6) + ((l >> 4) << 4)) ^ xorv);

    f32x4 acc[8][4] = {};
    uint32_t aold[8][4][2];   // packed bf16 (r0,r1),(r2,r3) per [mf][nf]
    bf16x8 aF[4], bF[4];

    auto issueA = [&](int T, int kh) {
        const int slot = ((T & 1) << 1) | kh;
        const int g = T / NT_L, lt = T % NT_L;
        const ushort* s = aPanel + aTh + (size_t)g * (256u * KT) + lt * 64 + kh * 32;
        char* d = dA + (slot << 14);
        __builtin_amdgcn_global_load_lds(GLOBAL_AS(s), LDS_AS(d), 16, 0, 0);
        __builtin_amdgcn_global_load_lds(GLOBAL_AS(s + (size_t)128 * KT), LDS_AS(d + 8192), 16, 0, 0);
    };
    auto issueB = [&](int T, int kh) {
        const int slot = ((T & 1) << 1) | kh;
        const int lt = T % NT_L;
        const ushort* s = Bt + bTh + lt * 64 + kh * 32;
        char* d = dB + (slot << 14);
        __builtin_amdgcn_global_load_lds(GLOBAL_AS(s), LDS_AS(d), 16, 0, 0);
        __builtin_amdgcn_global_load_lds(GLOBAL_AS(s + (size_t)128 * KT), LDS_AS(d + 8192), 16, 0, 0);
    };
    auto rdA = [&](int slot, int mb) {
        const char* p = (const char*)sm + (slot << 14) + preA + (mb << 12);
        aF[0] = *(const bf16x8*)(p);
        aF[1] = *(const bf16x8*)(p + 1024);
        aF[2] = *(const bf16x8*)(p + 2048);
        aF[3] = *(const bf16x8*)(p + 3072);
    };
    auto rdB = [&](int slot) {
        const char* p = (const char*)sm + (slot << 14) + preB;
        bF[0] = *(const bf16x8*)(p);
        bF[1] = *(const bf16x8*)(p + 1024);
        bF[2] = *(const bf16x8*)(p + 2048);
        bF[3] = *(const bf16x8*)(p + 3072);
    };
    auto mfma16 = [&](int mb) {
        __builtin_amdgcn_s_setprio(1);
#pragma unroll
        for (int mf = 0; mf < 4; ++mf)
#pragma unroll
            for (int nf = 0; nf < 4; ++nf)
                acc[mb * 4 + mf][nf] = __builtin_amdgcn_mfma_f32_16x16x32_bf16(
                    aF[mf], bF[nf], acc[mb * 4 + mf][nf], 0, 0, 0);
        __builtin_amdgcn_s_setprio(0);
    };

    // per-block-constant bias fragment (logical cols)
    float bv[4];
#pragma unroll
    for (int nf = 0; nf < 4; ++nf)
        bv[nf] = bias[bcol + (wc << 6) + nf * 16 + (l & 15)];

    int erow = 0;
    const int ecol = bcol + (wc << 6) + ((l & 15) << 2);   // permuted col base

    auto upk = [&](uint32_t p, int odd) -> float {
        return __uint_as_float(odd ? (p & 0xffff0000u) : (p << 16));
    };

    // pack acc -> aold (bf16), zero acc; remember the finished group's rows
    auto packzero = [&](int g) {
        erow = brow0 + (g - 1) * 256 + (wr << 7) + ((l >> 4) << 2);
#pragma unroll
        for (int mf = 0; mf < 8; ++mf)
#pragma unroll
            for (int nf = 0; nf < 4; ++nf) {
                asm("v_cvt_pk_bf16_f32 %0, %1, %2"
                    : "=v"(aold[mf][nf][0]) : "v"(acc[mf][nf][0]), "v"(acc[mf][nf][1]));
                asm("v_cvt_pk_bf16_f32 %0, %1, %2"
                    : "=v"(aold[mf][nf][1]) : "v"(acc[mf][nf][2]), "v"(acc[mf][nf][3]));
                acc[mf][nf] = f32x4{0.f, 0.f, 0.f, 0.f};
            }
    };

    // one spread-epilogue slice: gelu + packed 8B store for m-frag MF
    auto slice = [&](auto mfc) {
        constexpr int MF = mfc.value;
#pragma unroll
        for (int r = 0; r < 4; ++r) {
            float f0 = gelu_s(upk(aold[MF][0][r >> 1], r & 1) + bv[0]);
            float f1 = gelu_s(upk(aold[MF][1][r >> 1], r & 1) + bv[1]);
            float f2 = gelu_s(upk(aold[MF][2][r >> 1], r & 1) + bv[2]);
            float f3 = gelu_s(upk(aold[MF][3][r >> 1], r & 1) + bv[3]);
            uint32_t lo, hi;
            asm("v_cvt_pk_bf16_f32 %0, %1, %2" : "=v"(lo) : "v"(f0), "v"(f1));
            asm("v_cvt_pk_bf16_f32 %0, %1, %2" : "=v"(hi) : "v"(f2), "v"(f3));
            uint2 pv; pv.x = lo; pv.y = hi;
            *(uint2*)(outH + (size_t)(erow + MF * 16 + r) * N + ecol) = pv;
        }
    };

    auto tile_body = [&](int T_, bool sg, auto m0, auto m1, auto m2, auto m3) {
        const int s0_ = (T_ & 1) << 1;
        rdA(s0_, 0); rdB(s0_);
        SBAR();
        if (T_ + 1 < TT) issueB(T_ + 1, 1);
        mfma16(0);
        if (sg) slice(m0);
        SBAR();
        rdA(s0_, 1);
        SBAR();
        if (T_ + 2 < TT) issueA(T_ + 2, 0);
        mfma16(1);
        if (sg) slice(m1);
        SBAR();
        rdA(s0_ + 1, 0); rdB(s0_ + 1);
        SBAR();
        if (T_ + 2 < TT) issueB(T_ + 2, 0);
        mfma16(0);
        if (sg) slice(m2);
        SBAR();
        rdA(s0_ + 1, 1);
        SBAR();
        if (T_ + 2 < TT) issueA(T_ + 2, 1);
        mfma16(1);
        if (sg) slice(m3);
        __builtin_amdgcn_sched_barrier(0);
        if (T_ < TT - 2)       { asm volatile("s_waitcnt vmcnt(6)" ::: "memory"); }
        else if (T_ == TT - 2) { asm volatile("s_waitcnt vmcnt(0)" ::: "memory"); }
        SBAR();
    };

    // --- prologue: 7 units (tile 0 complete + 3 units of tile 1)
    issueA(0, 0); issueB(0, 0);
    issueA(0, 1); issueB(0, 1);
    issueA(1, 0); issueB(1, 0);
    issueA(1, 1);
    __builtin_amdgcn_sched_barrier(0);
    asm volatile("s_waitcnt vmcnt(6)" ::: "memory");
    SBAR();

#pragma unroll 1
    for (int g = 0; g < GROUPS; ++g) {
        if constexpr (SPREAD) { if (g > 0) packzero(g); }
        const bool sp1 = SPREAD && (g > 0);
#pragma unroll 1
        for (int lt = 0; lt < NT_L; lt += 2) {
            const int T0 = g * NT_L + lt;
            const bool sg = sp1 && (lt == 0);
            tile_body(T0,     sg, ic<0>{}, ic<1>{}, ic<2>{}, ic<3>{});
            tile_body(T0 + 1, sg, ic<4>{}, ic<5>{}, ic<6>{}, ic<7>{});
        }
    }

    // ---------------- final-group epilogue ----------------
    if constexpr (EPI == 0) {
        const int frow = brow0 + (GROUPS - 1) * 256 + (wr << 7) + ((l >> 4) << 2);
#pragma unroll
        for (int mf = 0; mf < 8; ++mf)
#pragma unroll
            for (int r = 0; r < 4; ++r) {
                float f0 = gelu_s(acc[mf][0][r] + bv[0]);
                float f1 = gelu_s(acc[mf][1][r] + bv[1]);
                float f2 = gelu_s(acc[mf][2][r] + bv[2]);
                float f3 = gelu_s(acc[mf][3][r] + bv[3]);
                uint32_t lo, hi;
                asm("v_cvt_pk_bf16_f32 %0, %1, %2" : "=v"(lo) : "v"(f0), "v"(f1));
                asm("v_cvt_pk_bf16_f32 %0, %1, %2" : "=v"(hi) : "v"(f2), "v"(f3));
                uint2 pv; pv.x = lo; pv.y = hi;
                *(uint2*)(outH + (size_t)(frow + mf * 16 + r) * N + ecol) = pv;
            }
    } else {
        const int rbase = brow0 + (wr << 7) + ((l >> 4) << 2);
        const int cbase = bcol + (wc << 6) + (l & 15);
#pragma unroll
        for (int mf = 0; mf < 8; ++mf) {
#pragma unroll
            for (int r = 0; r < 4; ++r) {
                const int row = rbase + mf * 16 + r;
                const float* x0 = resid + (size_t)row * 512;
                const float* x1 = resid + (size_t)rolled_row(row) * 512;
#pragma unroll
                for (int nf = 0; nf < 4; ++nf) {
                    const int col = cbase + nf * 16;
                    outF[(size_t)row * N + col] =
                        acc[mf][nf][r] + bv[nf] + x0[col] + x1[col];
                }
            }
        }
    }
}

__global__ __launch_bounds__(512, 2)
void mlp_gemm1(const ushort* __restrict__ A, const ushort* __restrict__ Bt,
               const float* __restrict__ bias, ushort* __restrict__ outH, int N) {
    gemm8p_body<0, 4, 512, 3>(A, Bt, bias, nullptr, outH, nullptr, N);
}

__global__ __launch_bounds__(512, 2)
void mlp_gemm2(const ushort* __restrict__ A, const ushort* __restrict__ Bt,
               const float* __restrict__ bias, const float* __restrict__ resid,
               float* __restrict__ outF, int N) {
    gemm8p_body<1, 1, 2048, 1>(A, Bt, bias, resid, nullptr, outF, N);
}

// ---------------------------------------------------------------------------
extern "C" void kernel_launch(void* const* d_in, const int* in_sizes, int n_in,
                              void* d_out, int out_size, void* d_ws, size_t ws_size,
                              hipStream_t stream) {
    const float* in = (const float*)d_in[0];
    const float* ln_g = (const float*)d_in[1];
    const float* ln_b = (const float*)d_in[2];
    const float* W1 = (const float*)d_in[3];
    const float* b1 = (const float*)d_in[4];
    const float* W2 = (const float*)d_in[5];
    const float* b2 = (const float*)d_in[6];
    float* out = (float*)d_out;

    char* ws = (char*)d_ws;
    ushort* normed = (ushort*)ws;                                  // 32 MB
    ushort* hbuf   = (ushort*)(ws + (size_t)32 * 1024 * 1024);     // 128 MB (k-permuted)
    ushort* W1T    = (ushort*)(ws + (size_t)160 * 1024 * 1024);    // 2 MB [2048][512]
    ushort* W2T    = (ushort*)(ws + (size_t)162 * 1024 * 1024);    // 2 MB [512][2048] k-permuted

    const int M = 32768;
    const int C = 512, C4 = 2048;

    ln_kernel<<<M, 128, 0, stream>>>(in, ln_g, ln_b, normed);
    transpose_cast<0><<<dim3(C4 / 32, C / 32), dim3(32, 8), 0, stream>>>(W1, W1T, C, C4);
    transpose_cast<1><<<dim3(C / 32, C4 / 32), dim3(32, 8), 0, stream>>>(W2, W2T, C4, C);

    mlp_gemm1<<<dim3(256), 512, 0, stream>>>(normed, W1T, b1, hbuf, C4);
    mlp_gemm2<<<dim3(256), 512, 0, stream>>>(hbuf, W2T, b2, in, out, C);
}

// Round 5
// 338.008 us; speedup vs baseline: 1.1150x; 1.1150x over previous
//
#include <hip/hip_runtime.h>
#include <hip/hip_bf16.h>
#include <cstdint>
#include <cstddef>

// ---------------------------------------------------------------------------
// SwinWindowTransformLayer: roll+add -> LayerNorm -> MLP(GELU) -> +x
// Round 5: attribution round. G1 loop-only diagnostic (no stores) + V_B fix:
// gelu/pack at group boundary, 4 packed uint2 stores right after each tile
// boundary (outside the counted-vmcnt window).
// ---------------------------------------------------------------------------

typedef short bf16x8 __attribute__((ext_vector_type(8)));
typedef float f32x4 __attribute__((ext_vector_type(4)));

#define GLOBAL_AS(p) ((__attribute__((address_space(1))) void*)(uintptr_t)(p))
#define LDS_AS(p)    ((__attribute__((address_space(3))) void*)(p))

template <int I> struct ic { static constexpr int value = I; };

static __device__ __forceinline__ ushort f2bf(float f) {
    uint32_t u = __float_as_uint(f);
    uint32_t r = (u + 0x7FFFu + ((u >> 16) & 1u)) >> 16;
    return (ushort)r;
}

// exact rewrite of tanh-gelu: 0.5v(1+tanh(u)) == v*sigmoid(2u)
static __device__ __forceinline__ float gelu_s(float v) {
    float v2 = v * v;
    float m = fmaf(0.07135481283f, v2, 1.5957691216f);
    float e = __expf(-v * m);
    return v * __builtin_amdgcn_rcpf(1.0f + e);
}

// roll by (-4,-4) on a 64x64 grid
static __device__ __forceinline__ int rolled_row(int row) {
    int b = row >> 12, n = row & 4095;
    int h = n >> 6, wv = n & 63;
    int n2 = (((h + 4) & 63) << 6) | ((wv + 4) & 63);
    return (b << 12) | n2;
}

#define SBAR() do { __builtin_amdgcn_sched_barrier(0); \
                    __builtin_amdgcn_s_barrier(); \
                    __builtin_amdgcn_sched_barrier(0); } while (0)

// ---------------------------------------------------------------------------
__global__ __launch_bounds__(128)
void ln_kernel(const float* __restrict__ in, const float* __restrict__ gamma,
               const float* __restrict__ beta, ushort* __restrict__ normed) {
    const int row = blockIdx.x;
    const int t = threadIdx.x;
    const int row2 = rolled_row(row);

    const float4* p0 = (const float4*)(in + (size_t)row * 512);
    const float4* p1 = (const float4*)(in + (size_t)row2 * 512);
    float4 a = p0[t], c = p1[t];
    float x0 = a.x + c.x, x1 = a.y + c.y, x2 = a.z + c.z, x3 = a.w + c.w;

    float s = x0 + x1 + x2 + x3;
    float sq = x0 * x0 + x1 * x1 + x2 * x2 + x3 * x3;
#pragma unroll
    for (int o = 32; o > 0; o >>= 1) {
        s += __shfl_xor(s, o);
        sq += __shfl_xor(sq, o);
    }
    __shared__ float red[4];
    if ((t & 63) == 0) { red[(t >> 6) * 2] = s; red[(t >> 6) * 2 + 1] = sq; }
    __syncthreads();
    s = red[0] + red[2];
    sq = red[1] + red[3];
    float mu = s * (1.0f / 512.0f);
    float var = sq * (1.0f / 512.0f) - mu * mu;
    float rs = rsqrtf(var + 1e-6f);

    float4 g = ((const float4*)gamma)[t];
    float4 be = ((const float4*)beta)[t];
    ushort4 o4;
    o4.x = f2bf((x0 - mu) * rs * g.x + be.x);
    o4.y = f2bf((x1 - mu) * rs * g.y + be.y);
    o4.z = f2bf((x2 - mu) * rs * g.z + be.z);
    o4.w = f2bf((x3 - mu) * rs * g.w + be.w);
    ((ushort4*)(normed + (size_t)row * 512))[t] = o4;
}

// ---------------------------------------------------------------------------
// transpose + cast fp32 [R][Ccols] -> bf16 [Ccols][R].
// PERM=1: permute k (within 64-blocks: nf*16+c -> c*4+nf) to match the
// permuted hbuf layout written by mlp_gemm1's epilogue.
// ---------------------------------------------------------------------------
template <int PERM>
__global__ __launch_bounds__(256)
void transpose_cast(const float* __restrict__ src, ushort* __restrict__ dst,
                    int R, int Ccols) {
    __shared__ float tile[32][33];
    const int bx = blockIdx.x * 32;
    const int by = blockIdx.y * 32;
    const int tx = threadIdx.x, ty = threadIdx.y;
#pragma unroll
    for (int i = 0; i < 32; i += 8)
        tile[ty + i][tx] = src[(size_t)(by + ty + i) * Ccols + bx + tx];
    __syncthreads();
    int k = by + tx;
    int kd = PERM ? ((k & ~63) | ((k & 15) << 2) | ((k >> 4) & 3)) : k;
#pragma unroll
    for (int i = 0; i < 32; i += 8)
        dst[(size_t)(bx + ty + i) * R + kd] = f2bf(tile[tx][ty + i]);
}

// ---------------------------------------------------------------------------
// Persistent 8-phase 256x256 GEMM body.
// MODE 0: G1: h = bf16(gelu(acc+bias)) k-permuted; gelu+pack at group
//         boundary, 4 uint2 stores right after each tile-boundary wait.
// MODE 1: G2: terminal out = acc + bias + resid[row] + resid[roll(row)].
// MODE 2: diagnostic: no stores at all; acc kept live via asm sinks.
// ---------------------------------------------------------------------------
template <int MODE, int GROUPS, int KT, int LOG2NCB>
__device__ __forceinline__ void gemm8p_body(
        const ushort* __restrict__ A, const ushort* __restrict__ Bt,
        const float* __restrict__ bias, const float* __restrict__ resid,
        ushort* __restrict__ outH, float* __restrict__ outF, int N) {
    constexpr int NT_L = KT / 64;
    constexpr int TT = GROUPS * NT_L;
    __shared__ __align__(16) char sm[131072];
    const int t = threadIdx.x;
    const int w = t >> 6, l = t & 63;
    const int wr = w >> 2, wc = w & 3;

    const int nwg = gridDim.x;
    const int bid = blockIdx.x;
    const int swz = (bid & 7) * (nwg >> 3) + (bid >> 3);
    const int cb = swz & ((1 << LOG2NCB) - 1);
    const int rgrp = swz >> LOG2NCB;
    const int brow0 = rgrp * (GROUPS * 256);
    const int bcol = cb << 8;

    const int kksw = (((t & 3) ^ ((t >> 4) & 3)) << 3);
    const size_t aTh = (size_t)(t >> 2) * KT + kksw;
    const size_t bTh = (size_t)(bcol + (t >> 2)) * KT + kksw;
    const ushort* const aPanel = A + (size_t)brow0 * KT;
    char* const dA = (char*)sm + (w << 10);
    char* const dB = dA + 65536;

    const int xorv = ((l >> 2) & 3) << 4;
    const int preA = ((((wr << 7) + (l & 15)) << 6) + ((l >> 4) << 4)) ^ xorv;
    const int preB = 65536 + (((((wc << 6) + (l & 15)) << 6) + ((l >> 4) << 4)) ^ xorv);

    f32x4 acc[8][4] = {};
    uint32_t pk[8][4][2];     // MODE0: packed gelu'd bf16, store layout
    bf16x8 aF[4], bF[4];

    auto issueA = [&](int T, int kh) {
        const int slot = ((T & 1) << 1) | kh;
        const int g = T / NT_L, lt = T % NT_L;
        const ushort* s = aPanel + aTh + (size_t)g * (256u * KT) + lt * 64 + kh * 32;
        char* d = dA + (slot << 14);
        __builtin_amdgcn_global_load_lds(GLOBAL_AS(s), LDS_AS(d), 16, 0, 0);
        __builtin_amdgcn_global_load_lds(GLOBAL_AS(s + (size_t)128 * KT), LDS_AS(d + 8192), 16, 0, 0);
    };
    auto issueB = [&](int T, int kh) {
        const int slot = ((T & 1) << 1) | kh;
        const int lt = T % NT_L;
        const ushort* s = Bt + bTh + lt * 64 + kh * 32;
        char* d = dB + (slot << 14);
        __builtin_amdgcn_global_load_lds(GLOBAL_AS(s), LDS_AS(d), 16, 0, 0);
        __builtin_amdgcn_global_load_lds(GLOBAL_AS(s + (size_t)128 * KT), LDS_AS(d + 8192), 16, 0, 0);
    };
    auto rdA = [&](int slot, int mb) {
        const char* p = (const char*)sm + (slot << 14) + preA + (mb << 12);
        aF[0] = *(const bf16x8*)(p);
        aF[1] = *(const bf16x8*)(p + 1024);
        aF[2] = *(const bf16x8*)(p + 2048);
        aF[3] = *(const bf16x8*)(p + 3072);
    };
    auto rdB = [&](int slot) {
        const char* p = (const char*)sm + (slot << 14) + preB;
        bF[0] = *(const bf16x8*)(p);
        bF[1] = *(const bf16x8*)(p + 1024);
        bF[2] = *(const bf16x8*)(p + 2048);
        bF[3] = *(const bf16x8*)(p + 3072);
    };
    auto mfma16 = [&](int mb) {
        __builtin_amdgcn_s_setprio(1);
#pragma unroll
        for (int mf = 0; mf < 4; ++mf)
#pragma unroll
            for (int nf = 0; nf < 4; ++nf)
                acc[mb * 4 + mf][nf] = __builtin_amdgcn_mfma_f32_16x16x32_bf16(
                    aF[mf], bF[nf], acc[mb * 4 + mf][nf], 0, 0, 0);
        __builtin_amdgcn_s_setprio(0);
    };

    float bv[4];
#pragma unroll
    for (int nf = 0; nf < 4; ++nf)
        bv[nf] = bias[bcol + (wc << 6) + nf * 16 + (l & 15)];

    int erow = 0;
    const int ecol = bcol + (wc << 6) + ((l & 15) << 2);   // permuted col base

    // gelu + pack group g's acc into pk (store layout), zero acc
    auto packgelu = [&](int g) {
        erow = brow0 + g * 256 + (wr << 7) + ((l >> 4) << 2);
#pragma unroll
        for (int mf = 0; mf < 8; ++mf)
#pragma unroll
            for (int r = 0; r < 4; ++r) {
                float f0 = gelu_s(acc[mf][0][r] + bv[0]);
                float f1 = gelu_s(acc[mf][1][r] + bv[1]);
                float f2 = gelu_s(acc[mf][2][r] + bv[2]);
                float f3 = gelu_s(acc[mf][3][r] + bv[3]);
                asm("v_cvt_pk_bf16_f32 %0, %1, %2" : "=v"(pk[mf][r][0]) : "v"(f0), "v"(f1));
                asm("v_cvt_pk_bf16_f32 %0, %1, %2" : "=v"(pk[mf][r][1]) : "v"(f2), "v"(f3));
            }
#pragma unroll
        for (int mf = 0; mf < 8; ++mf)
#pragma unroll
            for (int nf = 0; nf < 4; ++nf)
                acc[mf][nf] = f32x4{0.f, 0.f, 0.f, 0.f};
    };

    // 4 packed 8B stores for m-frag MF of the previously packed group
    auto slice = [&](auto mfc) {
        constexpr int MF = decltype(mfc)::value;
#pragma unroll
        for (int r = 0; r < 4; ++r) {
            uint2 pv; pv.x = pk[MF][r][0]; pv.y = pk[MF][r][1];
            *(uint2*)(outH + (size_t)(erow + MF * 16 + r) * N + ecol) = pv;
        }
    };

    auto tile_body = [&](int T_, auto mfc, bool sg) {
        const int s0_ = (T_ & 1) << 1;
        rdA(s0_, 0); rdB(s0_);
        SBAR();
        if (T_ + 1 < TT) issueB(T_ + 1, 1);
        mfma16(0);
        SBAR();
        rdA(s0_, 1);
        SBAR();
        if (T_ + 2 < TT) issueA(T_ + 2, 0);
        mfma16(1);
        SBAR();
        rdA(s0_ + 1, 0); rdB(s0_ + 1);
        SBAR();
        if (T_ + 2 < TT) issueB(T_ + 2, 0);
        mfma16(0);
        SBAR();
        rdA(s0_ + 1, 1);
        SBAR();
        if (T_ + 2 < TT) issueA(T_ + 2, 1);
        mfma16(1);
        __builtin_amdgcn_sched_barrier(0);
        if (T_ < TT - 2)       { asm volatile("s_waitcnt vmcnt(6)" ::: "memory"); }
        else if (T_ == TT - 2) { asm volatile("s_waitcnt vmcnt(0)" ::: "memory"); }
        SBAR();
        // stores AFTER the counted wait: they get a full tile to retire
        // before the next boundary's vmcnt(6) reaches them.
        if constexpr (MODE == 0) { if (sg) slice(mfc); }
    };

    // --- prologue
    issueA(0, 0); issueB(0, 0);
    issueA(0, 1); issueB(0, 1);
    issueA(1, 0); issueB(1, 0);
    issueA(1, 1);
    __builtin_amdgcn_sched_barrier(0);
    asm volatile("s_waitcnt vmcnt(6)" ::: "memory");
    SBAR();

    if constexpr (MODE == 0) {
#pragma unroll 1
        for (int g = 0; g < GROUPS; ++g) {
            if (g > 0) packgelu(g - 1);
            const bool sg = (g > 0);
            const int T0 = g * NT_L;
            // NT_L == 8: fully unrolled, one static-MF slice per tile
            tile_body(T0 + 0, ic<0>{}, sg);
            tile_body(T0 + 1, ic<1>{}, sg);
            tile_body(T0 + 2, ic<2>{}, sg);
            tile_body(T0 + 3, ic<3>{}, sg);
            tile_body(T0 + 4, ic<4>{}, sg);
            tile_body(T0 + 5, ic<5>{}, sg);
            tile_body(T0 + 6, ic<6>{}, sg);
            tile_body(T0 + 7, ic<7>{}, sg);
        }
        // terminal: last group's gelu + all 32 stores
        const int frow = brow0 + (GROUPS - 1) * 256 + (wr << 7) + ((l >> 4) << 2);
#pragma unroll
        for (int mf = 0; mf < 8; ++mf)
#pragma unroll
            for (int r = 0; r < 4; ++r) {
                float f0 = gelu_s(acc[mf][0][r] + bv[0]);
                float f1 = gelu_s(acc[mf][1][r] + bv[1]);
                float f2 = gelu_s(acc[mf][2][r] + bv[2]);
                float f3 = gelu_s(acc[mf][3][r] + bv[3]);
                uint32_t lo, hi;
                asm("v_cvt_pk_bf16_f32 %0, %1, %2" : "=v"(lo) : "v"(f0), "v"(f1));
                asm("v_cvt_pk_bf16_f32 %0, %1, %2" : "=v"(hi) : "v"(f2), "v"(f3));
                uint2 pv; pv.x = lo; pv.y = hi;
                *(uint2*)(outH + (size_t)(frow + mf * 16 + r) * N + ecol) = pv;
            }
    } else {
#pragma unroll 1
        for (int T = 0; T < TT; ++T)
            tile_body(T, ic<0>{}, false);

        if constexpr (MODE == 1) {
            const int rbase = brow0 + (wr << 7) + ((l >> 4) << 2);
            const int cbase = bcol + (wc << 6) + (l & 15);
#pragma unroll
            for (int mf = 0; mf < 8; ++mf) {
#pragma unroll
                for (int r = 0; r < 4; ++r) {
                    const int row = rbase + mf * 16 + r;
                    const float* x0 = resid + (size_t)row * 512;
                    const float* x1 = resid + (size_t)rolled_row(row) * 512;
#pragma unroll
                    for (int nf = 0; nf < 4; ++nf) {
                        const int col = cbase + nf * 16;
                        outF[(size_t)row * N + col] =
                            acc[mf][nf][r] + bv[nf] + x0[col] + x1[col];
                    }
                }
            }
        } else {
            // MODE 2: diagnostic — keep acc live, store nothing
#pragma unroll
            for (int mf = 0; mf < 8; ++mf)
#pragma unroll
                for (int nf = 0; nf < 4; ++nf)
                    asm volatile("" :: "v"(acc[mf][nf][0]), "v"(acc[mf][nf][1]),
                                       "v"(acc[mf][nf][2]), "v"(acc[mf][nf][3]));
        }
    }
}

__global__ __launch_bounds__(512, 2)
void mlp_gemm1(const ushort* __restrict__ A, const ushort* __restrict__ Bt,
               const float* __restrict__ bias, ushort* __restrict__ outH, int N) {
    gemm8p_body<0, 4, 512, 3>(A, Bt, bias, nullptr, outH, nullptr, N);
}

__global__ __launch_bounds__(512, 2)
void mlp_gemm1_diag(const ushort* __restrict__ A, const ushort* __restrict__ Bt,
                    const float* __restrict__ bias, int N) {
    gemm8p_body<2, 4, 512, 3>(A, Bt, bias, nullptr, nullptr, nullptr, N);
}

__global__ __launch_bounds__(512, 2)
void mlp_gemm2(const ushort* __restrict__ A, const ushort* __restrict__ Bt,
               const float* __restrict__ bias, const float* __restrict__ resid,
               float* __restrict__ outF, int N) {
    gemm8p_body<1, 1, 2048, 1>(A, Bt, bias, resid, nullptr, outF, N);
}

// ---------------------------------------------------------------------------
extern "C" void kernel_launch(void* const* d_in, const int* in_sizes, int n_in,
                              void* d_out, int out_size, void* d_ws, size_t ws_size,
                              hipStream_t stream) {
    const float* in = (const float*)d_in[0];
    const float* ln_g = (const float*)d_in[1];
    const float* ln_b = (const float*)d_in[2];
    const float* W1 = (const float*)d_in[3];
    const float* b1 = (const float*)d_in[4];
    const float* W2 = (const float*)d_in[5];
    const float* b2 = (const float*)d_in[6];
    float* out = (float*)d_out;

    char* ws = (char*)d_ws;
    ushort* normed = (ushort*)ws;                                  // 32 MB
    ushort* hbuf   = (ushort*)(ws + (size_t)32 * 1024 * 1024);     // 128 MB (k-permuted)
    ushort* W1T    = (ushort*)(ws + (size_t)160 * 1024 * 1024);    // 2 MB [2048][512]
    ushort* W2T    = (ushort*)(ws + (size_t)162 * 1024 * 1024);    // 2 MB [512][2048] k-permuted

    const int M = 32768;
    const int C = 512, C4 = 2048;

    ln_kernel<<<M, 128, 0, stream>>>(in, ln_g, ln_b, normed);
    transpose_cast<0><<<dim3(C4 / 32, C / 32), dim3(32, 8), 0, stream>>>(W1, W1T, C, C4);
    transpose_cast<1><<<dim3(C / 32, C4 / 32), dim3(32, 8), 0, stream>>>(W2, W2T, C4, C);

    // diagnostic: identical G1 loop, zero stores (per-dispatch time via rocprof)
    mlp_gemm1_diag<<<dim3(256), 512, 0, stream>>>(normed, W1T, b1, C4);
    mlp_gemm1<<<dim3(256), 512, 0, stream>>>(normed, W1T, b1, hbuf, C4);
    mlp_gemm2<<<dim3(256), 512, 0, stream>>>(hbuf, W2T, b2, in, out, C);
}

// Round 6
// 220.455 us; speedup vs baseline: 1.7096x; 1.5332x over previous
//
#include <hip/hip_runtime.h>
#include <hip/hip_bf16.h>
#include <cstdint>
#include <cstddef>

// ---------------------------------------------------------------------------
// SwinWindowTransformLayer: roll+add -> LayerNorm -> MLP(GELU) -> +x
// Round 6: G1 = R1's proven naive 128x128 structure + lean epilogue
// (sigmoid-gelu, packed uint2 stores to k-permuted hbuf). G2 = proven
// persistent 8-phase kernel, unchanged.
// ---------------------------------------------------------------------------

typedef short bf16x8 __attribute__((ext_vector_type(8)));
typedef float f32x4 __attribute__((ext_vector_type(4)));

#define GLOBAL_AS(p) ((__attribute__((address_space(1))) void*)(uintptr_t)(p))
#define LDS_AS(p)    ((__attribute__((address_space(3))) void*)(p))

static __device__ __forceinline__ ushort f2bf(float f) {
    uint32_t u = __float_as_uint(f);
    uint32_t r = (u + 0x7FFFu + ((u >> 16) & 1u)) >> 16;
    return (ushort)r;
}

// exact rewrite of tanh-gelu: 0.5v(1+tanh(u)) == v*sigmoid(2u)
static __device__ __forceinline__ float gelu_s(float v) {
    float v2 = v * v;
    float m = fmaf(0.07135481283f, v2, 1.5957691216f);
    float e = __expf(-v * m);
    return v * __builtin_amdgcn_rcpf(1.0f + e);
}

// roll by (-4,-4) on a 64x64 grid
static __device__ __forceinline__ int rolled_row(int row) {
    int b = row >> 12, n = row & 4095;
    int h = n >> 6, wv = n & 63;
    int n2 = (((h + 4) & 63) << 6) | ((wv + 4) & 63);
    return (b << 12) | n2;
}

#define SBAR() do { __builtin_amdgcn_sched_barrier(0); \
                    __builtin_amdgcn_s_barrier(); \
                    __builtin_amdgcn_sched_barrier(0); } while (0)

// ---------------------------------------------------------------------------
__global__ __launch_bounds__(128)
void ln_kernel(const float* __restrict__ in, const float* __restrict__ gamma,
               const float* __restrict__ beta, ushort* __restrict__ normed) {
    const int row = blockIdx.x;
    const int t = threadIdx.x;
    const int row2 = rolled_row(row);

    const float4* p0 = (const float4*)(in + (size_t)row * 512);
    const float4* p1 = (const float4*)(in + (size_t)row2 * 512);
    float4 a = p0[t], c = p1[t];
    float x0 = a.x + c.x, x1 = a.y + c.y, x2 = a.z + c.z, x3 = a.w + c.w;

    float s = x0 + x1 + x2 + x3;
    float sq = x0 * x0 + x1 * x1 + x2 * x2 + x3 * x3;
#pragma unroll
    for (int o = 32; o > 0; o >>= 1) {
        s += __shfl_xor(s, o);
        sq += __shfl_xor(sq, o);
    }
    __shared__ float red[4];
    if ((t & 63) == 0) { red[(t >> 6) * 2] = s; red[(t >> 6) * 2 + 1] = sq; }
    __syncthreads();
    s = red[0] + red[2];
    sq = red[1] + red[3];
    float mu = s * (1.0f / 512.0f);
    float var = sq * (1.0f / 512.0f) - mu * mu;
    float rs = rsqrtf(var + 1e-6f);

    float4 g = ((const float4*)gamma)[t];
    float4 be = ((const float4*)beta)[t];
    ushort4 o4;
    o4.x = f2bf((x0 - mu) * rs * g.x + be.x);
    o4.y = f2bf((x1 - mu) * rs * g.y + be.y);
    o4.z = f2bf((x2 - mu) * rs * g.z + be.z);
    o4.w = f2bf((x3 - mu) * rs * g.w + be.w);
    ((ushort4*)(normed + (size_t)row * 512))[t] = o4;
}

// ---------------------------------------------------------------------------
// transpose + cast fp32 [R][Ccols] -> bf16 [Ccols][R].
// PERM=1: permute k (within 64-blocks: nf*16+c -> c*4+nf) to match the
// permuted hbuf layout written by mlp_gemm1's epilogue.
// ---------------------------------------------------------------------------
template <int PERM>
__global__ __launch_bounds__(256)
void transpose_cast(const float* __restrict__ src, ushort* __restrict__ dst,
                    int R, int Ccols) {
    __shared__ float tile[32][33];
    const int bx = blockIdx.x * 32;
    const int by = blockIdx.y * 32;
    const int tx = threadIdx.x, ty = threadIdx.y;
#pragma unroll
    for (int i = 0; i < 32; i += 8)
        tile[ty + i][tx] = src[(size_t)(by + ty + i) * Ccols + bx + tx];
    __syncthreads();
    int k = by + tx;
    int kd = PERM ? ((k & ~63) | ((k & 15) << 2) | ((k >> 4) & 3)) : k;
#pragma unroll
    for (int i = 0; i < 32; i += 8)
        dst[(size_t)(bx + ty + i) * R + kd] = f2bf(tile[tx][ty + i]);
}

// ---------------------------------------------------------------------------
// G1: h = bf16(gelu(normed @ W1 + b1)), k-permuted packed stores.
// R1-proven structure: 128x128 tile, BK=32, 256 thr (4 waves 2x2),
// 4x4 16x16x32 frags/wave, 2-barrier K-loop, global_load_lds width 16.
// ---------------------------------------------------------------------------
__global__ __launch_bounds__(256)
void mlp_gemm1(const ushort* __restrict__ A, const ushort* __restrict__ Bt,
               const float* __restrict__ bias, ushort* __restrict__ outH) {
    constexpr int K = 512, N = 2048, BK = 32;
    __shared__ ushort Asm[128 * BK];
    __shared__ ushort Bsm[128 * BK];

    const int t = threadIdx.x;
    const int w = t >> 6, l = t & 63;
    const int wr = w >> 1, wc = w & 1;
    const int brow = blockIdx.y * 128;
    const int bcol = blockIdx.x * 128;

    f32x4 acc[4][4] = {};

    const int arow = t >> 2;          // 0..63
    const int acol = (t & 3) * 8;     // k-elem offset
    const size_t aBase = (size_t)(brow + arow) * K + acol;
    const size_t bBase = (size_t)(bcol + arow) * K + acol;
    char* ldsA = (char*)Asm + w * 1024;   // wave-uniform dest base
    char* ldsB = (char*)Bsm + w * 1024;

    const int kb = (l >> 4) * 8;
    const int rA = l & 15;

    for (int k0 = 0; k0 < K; k0 += BK) {
        __builtin_amdgcn_global_load_lds(GLOBAL_AS(A + aBase + k0), LDS_AS(ldsA), 16, 0, 0);
        __builtin_amdgcn_global_load_lds(GLOBAL_AS(A + aBase + (size_t)64 * K + k0), LDS_AS(ldsA + 4096), 16, 0, 0);
        __builtin_amdgcn_global_load_lds(GLOBAL_AS(Bt + bBase + k0), LDS_AS(ldsB), 16, 0, 0);
        __builtin_amdgcn_global_load_lds(GLOBAL_AS(Bt + bBase + (size_t)64 * K + k0), LDS_AS(ldsB + 4096), 16, 0, 0);
        __syncthreads();  // drains vmcnt -> tiles complete

        bf16x8 aF[4], bF[4];
#pragma unroll
        for (int i = 0; i < 4; ++i)
            aF[i] = *(const bf16x8*)&Asm[(wr * 64 + i * 16 + rA) * BK + kb];
#pragma unroll
        for (int j = 0; j < 4; ++j)
            bF[j] = *(const bf16x8*)&Bsm[(wc * 64 + j * 16 + rA) * BK + kb];

#pragma unroll
        for (int i = 0; i < 4; ++i)
#pragma unroll
            for (int j = 0; j < 4; ++j)
                acc[i][j] = __builtin_amdgcn_mfma_f32_16x16x32_bf16(aF[i], bF[j], acc[i][j], 0, 0, 0);
        __syncthreads();
    }

    // lean epilogue: gelu_s + packed uint2 stores (k-permuted layout:
    // logical col wc*64 + j*16 + cn  ->  storage col wc*64 + cn*4 + j)
    const int cm = (l >> 4) << 2;
    const int cn = l & 15;
    float bvv[4];
#pragma unroll
    for (int j = 0; j < 4; ++j)
        bvv[j] = bias[bcol + wc * 64 + j * 16 + cn];
    const int ecol = bcol + wc * 64 + (cn << 2);
#pragma unroll
    for (int i = 0; i < 4; ++i) {
#pragma unroll
        for (int r = 0; r < 4; ++r) {
            const int row = brow + wr * 64 + i * 16 + cm + r;
            float f0 = gelu_s(acc[i][0][r] + bvv[0]);
            float f1 = gelu_s(acc[i][1][r] + bvv[1]);
            float f2 = gelu_s(acc[i][2][r] + bvv[2]);
            float f3 = gelu_s(acc[i][3][r] + bvv[3]);
            uint32_t lo, hi;
            asm("v_cvt_pk_bf16_f32 %0, %1, %2" : "=v"(lo) : "v"(f0), "v"(f1));
            asm("v_cvt_pk_bf16_f32 %0, %1, %2" : "=v"(hi) : "v"(f2), "v"(f3));
            uint2 pv; pv.x = lo; pv.y = hi;
            *(uint2*)(outH + (size_t)row * N + ecol) = pv;
        }
    }
}

// ---------------------------------------------------------------------------
// G2: out = hbuf @ W2 + b2 + resid[row] + resid[roll(row)].
// Proven persistent 8-phase 256x256 kernel (R3/R5 MODE 1), KT=2048, TT=32.
// ---------------------------------------------------------------------------
__global__ __launch_bounds__(512, 2)
void mlp_gemm2(const ushort* __restrict__ A, const ushort* __restrict__ Bt,
               const float* __restrict__ bias, const float* __restrict__ resid,
               float* __restrict__ outF) {
    constexpr int KT = 2048, TT = 32, N = 512;
    __shared__ __align__(16) char sm[131072];
    const int t = threadIdx.x;
    const int w = t >> 6, l = t & 63;
    const int wr = w >> 2, wc = w & 3;

    const int nwg = gridDim.x;
    const int bid = blockIdx.x;
    const int swz = (bid & 7) * (nwg >> 3) + (bid >> 3);
    const int cb = swz & 1;
    const int rgrp = swz >> 1;
    const int brow0 = rgrp * 256;
    const int bcol = cb << 8;

    const int kksw = (((t & 3) ^ ((t >> 4) & 3)) << 3);
    const size_t aTh = (size_t)(t >> 2) * KT + kksw;
    const size_t bTh = (size_t)(bcol + (t >> 2)) * KT + kksw;
    const ushort* const aPanel = A + (size_t)brow0 * KT;
    char* const dA = (char*)sm + (w << 10);
    char* const dB = dA + 65536;

    const int xorv = ((l >> 2) & 3) << 4;
    const int preA = ((((wr << 7) + (l & 15)) << 6) + ((l >> 4) << 4)) ^ xorv;
    const int preB = 65536 + (((((wc << 6) + (l & 15)) << 6) + ((l >> 4) << 4)) ^ xorv);

    f32x4 acc[8][4] = {};
    bf16x8 aF[4], bF[4];

    auto issueA = [&](int T, int kh) {
        const int slot = ((T & 1) << 1) | kh;
        const ushort* s = aPanel + aTh + T * 64 + kh * 32;
        char* d = dA + (slot << 14);
        __builtin_amdgcn_global_load_lds(GLOBAL_AS(s), LDS_AS(d), 16, 0, 0);
        __builtin_amdgcn_global_load_lds(GLOBAL_AS(s + (size_t)128 * KT), LDS_AS(d + 8192), 16, 0, 0);
    };
    auto issueB = [&](int T, int kh) {
        const int slot = ((T & 1) << 1) | kh;
        const ushort* s = Bt + bTh + T * 64 + kh * 32;
        char* d = dB + (slot << 14);
        __builtin_amdgcn_global_load_lds(GLOBAL_AS(s), LDS_AS(d), 16, 0, 0);
        __builtin_amdgcn_global_load_lds(GLOBAL_AS(s + (size_t)128 * KT), LDS_AS(d + 8192), 16, 0, 0);
    };
    auto rdA = [&](int slot, int mb) {
        const char* p = (const char*)sm + (slot << 14) + preA + (mb << 12);
        aF[0] = *(const bf16x8*)(p);
        aF[1] = *(const bf16x8*)(p + 1024);
        aF[2] = *(const bf16x8*)(p + 2048);
        aF[3] = *(const bf16x8*)(p + 3072);
    };
    auto rdB = [&](int slot) {
        const char* p = (const char*)sm + (slot << 14) + preB;
        bF[0] = *(const bf16x8*)(p);
        bF[1] = *(const bf16x8*)(p + 1024);
        bF[2] = *(const bf16x8*)(p + 2048);
        bF[3] = *(const bf16x8*)(p + 3072);
    };
    auto mfma16 = [&](int mb) {
        __builtin_amdgcn_s_setprio(1);
#pragma unroll
        for (int mf = 0; mf < 4; ++mf)
#pragma unroll
            for (int nf = 0; nf < 4; ++nf)
                acc[mb * 4 + mf][nf] = __builtin_amdgcn_mfma_f32_16x16x32_bf16(
                    aF[mf], bF[nf], acc[mb * 4 + mf][nf], 0, 0, 0);
        __builtin_amdgcn_s_setprio(0);
    };

    float bv[4];
#pragma unroll
    for (int nf = 0; nf < 4; ++nf)
        bv[nf] = bias[bcol + (wc << 6) + nf * 16 + (l & 15)];

    // prologue: 7 units
    issueA(0, 0); issueB(0, 0);
    issueA(0, 1); issueB(0, 1);
    issueA(1, 0); issueB(1, 0);
    issueA(1, 1);
    __builtin_amdgcn_sched_barrier(0);
    asm volatile("s_waitcnt vmcnt(6)" ::: "memory");
    SBAR();

#pragma unroll 1
    for (int T = 0; T < TT; ++T) {
        const int s0 = (T & 1) << 1;
        rdA(s0, 0); rdB(s0);
        SBAR();
        if (T + 1 < TT) issueB(T + 1, 1);
        mfma16(0);
        SBAR();
        rdA(s0, 1);
        SBAR();
        if (T + 2 < TT) issueA(T + 2, 0);
        mfma16(1);
        SBAR();
        rdA(s0 + 1, 0); rdB(s0 + 1);
        SBAR();
        if (T + 2 < TT) issueB(T + 2, 0);
        mfma16(0);
        SBAR();
        rdA(s0 + 1, 1);
        SBAR();
        if (T + 2 < TT) issueA(T + 2, 1);
        mfma16(1);
        __builtin_amdgcn_sched_barrier(0);
        if (T < TT - 2)       { asm volatile("s_waitcnt vmcnt(6)" ::: "memory"); }
        else if (T == TT - 2) { asm volatile("s_waitcnt vmcnt(0)" ::: "memory"); }
        SBAR();
    }

    const int rbase = brow0 + (wr << 7) + ((l >> 4) << 2);
    const int cbase = bcol + (wc << 6) + (l & 15);
#pragma unroll
    for (int mf = 0; mf < 8; ++mf) {
#pragma unroll
        for (int r = 0; r < 4; ++r) {
            const int row = rbase + mf * 16 + r;
            const float* x0 = resid + (size_t)row * 512;
            const float* x1 = resid + (size_t)rolled_row(row) * 512;
#pragma unroll
            for (int nf = 0; nf < 4; ++nf) {
                const int col = cbase + nf * 16;
                outF[(size_t)row * N + col] =
                    acc[mf][nf][r] + bv[nf] + x0[col] + x1[col];
            }
        }
    }
}

// ---------------------------------------------------------------------------
extern "C" void kernel_launch(void* const* d_in, const int* in_sizes, int n_in,
                              void* d_out, int out_size, void* d_ws, size_t ws_size,
                              hipStream_t stream) {
    const float* in = (const float*)d_in[0];
    const float* ln_g = (const float*)d_in[1];
    const float* ln_b = (const float*)d_in[2];
    const float* W1 = (const float*)d_in[3];
    const float* b1 = (const float*)d_in[4];
    const float* W2 = (const float*)d_in[5];
    const float* b2 = (const float*)d_in[6];
    float* out = (float*)d_out;

    char* ws = (char*)d_ws;
    ushort* normed = (ushort*)ws;                                  // 32 MB
    ushort* hbuf   = (ushort*)(ws + (size_t)32 * 1024 * 1024);     // 128 MB (k-permuted)
    ushort* W1T    = (ushort*)(ws + (size_t)160 * 1024 * 1024);    // 2 MB [2048][512]
    ushort* W2T    = (ushort*)(ws + (size_t)162 * 1024 * 1024);    // 2 MB [512][2048] k-permuted

    const int M = 32768;
    const int C = 512, C4 = 2048;

    ln_kernel<<<M, 128, 0, stream>>>(in, ln_g, ln_b, normed);
    transpose_cast<0><<<dim3(C4 / 32, C / 32), dim3(32, 8), 0, stream>>>(W1, W1T, C, C4);
    transpose_cast<1><<<dim3(C / 32, C4 / 32), dim3(32, 8), 0, stream>>>(W2, W2T, C4, C);

    // G1: [32768,512]x[512,2048] -> gelu -> bf16 h (k-permuted), 128^2 tiles
    mlp_gemm1<<<dim3(C4 / 128, M / 128), 256, 0, stream>>>(normed, W1T, b1, hbuf);
    // G2: [32768,2048]x[2048,512] + bias + x -> out, persistent 8-phase
    mlp_gemm2<<<dim3(256), 512, 0, stream>>>(hbuf, W2T, b2, in, out);
}

// Round 7
// 217.837 us; speedup vs baseline: 1.7302x; 1.0120x over previous
//
#include <hip/hip_runtime.h>
#include <hip/hip_bf16.h>
#include <cstdint>
#include <cstddef>

// ---------------------------------------------------------------------------
// SwinWindowTransformLayer: roll+add -> LayerNorm -> MLP(GELU) -> +x
// Round 7: G1 = m97 128x128 structure + XOR-swizzled LDS (G2's proven
// kksw/xorv pair) + XCD row-panel-major block ordering. G2 = proven 8-phase
// loop + R2's proven LDS-repack epilogue (coalesced resid reads / full-line
// stores).
// ---------------------------------------------------------------------------

typedef short bf16x8 __attribute__((ext_vector_type(8)));
typedef float f32x4 __attribute__((ext_vector_type(4)));

#define GLOBAL_AS(p) ((__attribute__((address_space(1))) void*)(uintptr_t)(p))
#define LDS_AS(p)    ((__attribute__((address_space(3))) void*)(p))

static __device__ __forceinline__ ushort f2bf(float f) {
    uint32_t u = __float_as_uint(f);
    uint32_t r = (u + 0x7FFFu + ((u >> 16) & 1u)) >> 16;
    return (ushort)r;
}

// exact rewrite of tanh-gelu: 0.5v(1+tanh(u)) == v*sigmoid(2u)
static __device__ __forceinline__ float gelu_s(float v) {
    float v2 = v * v;
    float m = fmaf(0.07135481283f, v2, 1.5957691216f);
    float e = __expf(-v * m);
    return v * __builtin_amdgcn_rcpf(1.0f + e);
}

// roll by (-4,-4) on a 64x64 grid
static __device__ __forceinline__ int rolled_row(int row) {
    int b = row >> 12, n = row & 4095;
    int h = n >> 6, wv = n & 63;
    int n2 = (((h + 4) & 63) << 6) | ((wv + 4) & 63);
    return (b << 12) | n2;
}

#define SBAR() do { __builtin_amdgcn_sched_barrier(0); \
                    __builtin_amdgcn_s_barrier(); \
                    __builtin_amdgcn_sched_barrier(0); } while (0)

// ---------------------------------------------------------------------------
__global__ __launch_bounds__(128)
void ln_kernel(const float* __restrict__ in, const float* __restrict__ gamma,
               const float* __restrict__ beta, ushort* __restrict__ normed) {
    const int row = blockIdx.x;
    const int t = threadIdx.x;
    const int row2 = rolled_row(row);

    const float4* p0 = (const float4*)(in + (size_t)row * 512);
    const float4* p1 = (const float4*)(in + (size_t)row2 * 512);
    float4 a = p0[t], c = p1[t];
    float x0 = a.x + c.x, x1 = a.y + c.y, x2 = a.z + c.z, x3 = a.w + c.w;

    float s = x0 + x1 + x2 + x3;
    float sq = x0 * x0 + x1 * x1 + x2 * x2 + x3 * x3;
#pragma unroll
    for (int o = 32; o > 0; o >>= 1) {
        s += __shfl_xor(s, o);
        sq += __shfl_xor(sq, o);
    }
    __shared__ float red[4];
    if ((t & 63) == 0) { red[(t >> 6) * 2] = s; red[(t >> 6) * 2 + 1] = sq; }
    __syncthreads();
    s = red[0] + red[2];
    sq = red[1] + red[3];
    float mu = s * (1.0f / 512.0f);
    float var = sq * (1.0f / 512.0f) - mu * mu;
    float rs = rsqrtf(var + 1e-6f);

    float4 g = ((const float4*)gamma)[t];
    float4 be = ((const float4*)beta)[t];
    ushort4 o4;
    o4.x = f2bf((x0 - mu) * rs * g.x + be.x);
    o4.y = f2bf((x1 - mu) * rs * g.y + be.y);
    o4.z = f2bf((x2 - mu) * rs * g.z + be.z);
    o4.w = f2bf((x3 - mu) * rs * g.w + be.w);
    ((ushort4*)(normed + (size_t)row * 512))[t] = o4;
}

// ---------------------------------------------------------------------------
// transpose + cast fp32 [R][Ccols] -> bf16 [Ccols][R].
// PERM=1: permute k (within 64-blocks: nf*16+c -> c*4+nf) to match the
// permuted hbuf layout written by mlp_gemm1's epilogue.
// ---------------------------------------------------------------------------
template <int PERM>
__global__ __launch_bounds__(256)
void transpose_cast(const float* __restrict__ src, ushort* __restrict__ dst,
                    int R, int Ccols) {
    __shared__ float tile[32][33];
    const int bx = blockIdx.x * 32;
    const int by = blockIdx.y * 32;
    const int tx = threadIdx.x, ty = threadIdx.y;
#pragma unroll
    for (int i = 0; i < 32; i += 8)
        tile[ty + i][tx] = src[(size_t)(by + ty + i) * Ccols + bx + tx];
    __syncthreads();
    int k = by + tx;
    int kd = PERM ? ((k & ~63) | ((k & 15) << 2) | ((k >> 4) & 3)) : k;
#pragma unroll
    for (int i = 0; i < 32; i += 8)
        dst[(size_t)(bx + ty + i) * R + kd] = f2bf(tile[tx][ty + i]);
}

// ---------------------------------------------------------------------------
// G1: h = bf16(gelu(normed @ W1 + b1)), k-permuted packed stores.
// 128x128 tile, BK=32, 256 thr (4 waves 2x2), 2-barrier K-loop,
// XOR-swizzled LDS (pre-swizzled global source + swizzled ds_read chunk),
// XCD row-panel-major block ordering.
// ---------------------------------------------------------------------------
__global__ __launch_bounds__(256)
void mlp_gemm1(const ushort* __restrict__ A, const ushort* __restrict__ Bt,
               const float* __restrict__ bias, ushort* __restrict__ outH) {
    constexpr int K = 512, N = 2048, BK = 32;
    __shared__ ushort Asm[128 * BK];
    __shared__ ushort Bsm[128 * BK];

    const int t = threadIdx.x;
    const int w = t >> 6, l = t & 63;
    const int wr = w >> 1, wc = w & 1;

    // XCD-aware ordering: xcd = bid&7 owns 32 row-panels; within an XCD the
    // 16 col-blocks of one row-panel are consecutive -> A-panel stays L2-hot.
    const int bid = blockIdx.x;
    const int xcd = bid & 7, idx = bid >> 3;
    const int brow = ((xcd << 5) + (idx >> 4)) << 7;   // (xcd*32 + panel)*128
    const int bcol = (idx & 15) << 7;

    f32x4 acc[4][4] = {};

    // staging: thread t -> row t>>2, k-chunk pre-swizzled (inverse of read XOR)
    const int arow = t >> 2;
    const int kchunk = (((t & 3) ^ ((t >> 4) & 3)) << 3);   // k elems
    const size_t aBase = (size_t)(brow + arow) * K + kchunk;
    const size_t bBase = (size_t)(bcol + arow) * K + kchunk;
    char* ldsA = (char*)Asm + w * 1024;   // wave-uniform dest base
    char* ldsB = (char*)Bsm + w * 1024;

    // fragment reads: row*64 + swizzled 16B chunk
    const int slotA = (((l >> 4) ^ ((l >> 2) & 3)) << 4);   // byte offset
    const int rA = l & 63 & 15;

    for (int k0 = 0; k0 < K; k0 += BK) {
        __builtin_amdgcn_global_load_lds(GLOBAL_AS(A + aBase + k0), LDS_AS(ldsA), 16, 0, 0);
        __builtin_amdgcn_global_load_lds(GLOBAL_AS(A + aBase + (size_t)64 * K + k0), LDS_AS(ldsA + 4096), 16, 0, 0);
        __builtin_amdgcn_global_load_lds(GLOBAL_AS(Bt + bBase + k0), LDS_AS(ldsB), 16, 0, 0);
        __builtin_amdgcn_global_load_lds(GLOBAL_AS(Bt + bBase + (size_t)64 * K + k0), LDS_AS(ldsB + 4096), 16, 0, 0);
        __syncthreads();  // drains vmcnt -> tiles complete

        bf16x8 aF[4], bF[4];
#pragma unroll
        for (int i = 0; i < 4; ++i)
            aF[i] = *(const bf16x8*)((const char*)Asm + (wr * 64 + i * 16 + rA) * 64 + slotA);
#pragma unroll
        for (int j = 0; j < 4; ++j)
            bF[j] = *(const bf16x8*)((const char*)Bsm + (wc * 64 + j * 16 + rA) * 64 + slotA);

#pragma unroll
        for (int i = 0; i < 4; ++i)
#pragma unroll
            for (int j = 0; j < 4; ++j)
                acc[i][j] = __builtin_amdgcn_mfma_f32_16x16x32_bf16(aF[i], bF[j], acc[i][j], 0, 0, 0);
        __syncthreads();
    }

    // lean epilogue: gelu_s + packed uint2 stores (k-permuted layout)
    const int cm = (l >> 4) << 2;
    const int cn = l & 15;
    float bvv[4];
#pragma unroll
    for (int j = 0; j < 4; ++j)
        bvv[j] = bias[bcol + wc * 64 + j * 16 + cn];
    const int ecol = bcol + wc * 64 + (cn << 2);
#pragma unroll
    for (int i = 0; i < 4; ++i) {
#pragma unroll
        for (int r = 0; r < 4; ++r) {
            const int row = brow + wr * 64 + i * 16 + cm + r;
            float f0 = gelu_s(acc[i][0][r] + bvv[0]);
            float f1 = gelu_s(acc[i][1][r] + bvv[1]);
            float f2 = gelu_s(acc[i][2][r] + bvv[2]);
            float f3 = gelu_s(acc[i][3][r] + bvv[3]);
            uint32_t lo, hi;
            asm("v_cvt_pk_bf16_f32 %0, %1, %2" : "=v"(lo) : "v"(f0), "v"(f1));
            asm("v_cvt_pk_bf16_f32 %0, %1, %2" : "=v"(hi) : "v"(f2), "v"(f3));
            uint2 pv; pv.x = lo; pv.y = hi;
            *(uint2*)(outH + (size_t)row * N + ecol) = pv;
        }
    }
}

// ---------------------------------------------------------------------------
// G2: out = hbuf @ W2 + b2 + resid[row] + resid[roll(row)].
// Proven persistent 8-phase 256x256 loop (KT=2048, TT=32) + R2's proven
// LDS-repack epilogue (two 128-row f32 halves, coalesced resid/stores).
// ---------------------------------------------------------------------------
__global__ __launch_bounds__(512, 2)
void mlp_gemm2(const ushort* __restrict__ A, const ushort* __restrict__ Bt,
               const float* __restrict__ bias, const float* __restrict__ resid,
               float* __restrict__ outF) {
    constexpr int KT = 2048, TT = 32, N = 512;
    __shared__ __align__(16) char sm[131072];
    const int t = threadIdx.x;
    const int w = t >> 6, l = t & 63;
    const int wr = w >> 2, wc = w & 3;

    const int nwg = gridDim.x;
    const int bid = blockIdx.x;
    const int swz = (bid & 7) * (nwg >> 3) + (bid >> 3);
    const int cb = swz & 1;
    const int rgrp = swz >> 1;
    const int brow0 = rgrp * 256;
    const int bcol = cb << 8;

    const int kksw = (((t & 3) ^ ((t >> 4) & 3)) << 3);
    const size_t aTh = (size_t)(t >> 2) * KT + kksw;
    const size_t bTh = (size_t)(bcol + (t >> 2)) * KT + kksw;
    const ushort* const aPanel = A + (size_t)brow0 * KT;
    char* const dA = (char*)sm + (w << 10);
    char* const dB = dA + 65536;

    const int xorv = ((l >> 2) & 3) << 4;
    const int preA = ((((wr << 7) + (l & 15)) << 6) + ((l >> 4) << 4)) ^ xorv;
    const int preB = 65536 + (((((wc << 6) + (l & 15)) << 6) + ((l >> 4) << 4)) ^ xorv);

    f32x4 acc[8][4] = {};
    bf16x8 aF[4], bF[4];

    auto issueA = [&](int T, int kh) {
        const int slot = ((T & 1) << 1) | kh;
        const ushort* s = aPanel + aTh + T * 64 + kh * 32;
        char* d = dA + (slot << 14);
        __builtin_amdgcn_global_load_lds(GLOBAL_AS(s), LDS_AS(d), 16, 0, 0);
        __builtin_amdgcn_global_load_lds(GLOBAL_AS(s + (size_t)128 * KT), LDS_AS(d + 8192), 16, 0, 0);
    };
    auto issueB = [&](int T, int kh) {
        const int slot = ((T & 1) << 1) | kh;
        const ushort* s = Bt + bTh + T * 64 + kh * 32;
        char* d = dB + (slot << 14);
        __builtin_amdgcn_global_load_lds(GLOBAL_AS(s), LDS_AS(d), 16, 0, 0);
        __builtin_amdgcn_global_load_lds(GLOBAL_AS(s + (size_t)128 * KT), LDS_AS(d + 8192), 16, 0, 0);
    };
    auto rdA = [&](int slot, int mb) {
        const char* p = (const char*)sm + (slot << 14) + preA + (mb << 12);
        aF[0] = *(const bf16x8*)(p);
        aF[1] = *(const bf16x8*)(p + 1024);
        aF[2] = *(const bf16x8*)(p + 2048);
        aF[3] = *(const bf16x8*)(p + 3072);
    };
    auto rdB = [&](int slot) {
        const char* p = (const char*)sm + (slot << 14) + preB;
        bF[0] = *(const bf16x8*)(p);
        bF[1] = *(const bf16x8*)(p + 1024);
        bF[2] = *(const bf16x8*)(p + 2048);
        bF[3] = *(const bf16x8*)(p + 3072);
    };
    auto mfma16 = [&](int mb) {
        __builtin_amdgcn_s_setprio(1);
#pragma unroll
        for (int mf = 0; mf < 4; ++mf)
#pragma unroll
            for (int nf = 0; nf < 4; ++nf)
                acc[mb * 4 + mf][nf] = __builtin_amdgcn_mfma_f32_16x16x32_bf16(
                    aF[mf], bF[nf], acc[mb * 4 + mf][nf], 0, 0, 0);
        __builtin_amdgcn_s_setprio(0);
    };

    // prologue: 7 units
    issueA(0, 0); issueB(0, 0);
    issueA(0, 1); issueB(0, 1);
    issueA(1, 0); issueB(1, 0);
    issueA(1, 1);
    __builtin_amdgcn_sched_barrier(0);
    asm volatile("s_waitcnt vmcnt(6)" ::: "memory");
    SBAR();

#pragma unroll 1
    for (int T = 0; T < TT; ++T) {
        const int s0 = (T & 1) << 1;
        rdA(s0, 0); rdB(s0);
        SBAR();
        if (T + 1 < TT) issueB(T + 1, 1);
        mfma16(0);
        SBAR();
        rdA(s0, 1);
        SBAR();
        if (T + 2 < TT) issueA(T + 2, 0);
        mfma16(1);
        SBAR();
        rdA(s0 + 1, 0); rdB(s0 + 1);
        SBAR();
        if (T + 2 < TT) issueB(T + 2, 0);
        mfma16(0);
        SBAR();
        rdA(s0 + 1, 1);
        SBAR();
        if (T + 2 < TT) issueA(T + 2, 1);
        mfma16(1);
        __builtin_amdgcn_sched_barrier(0);
        if (T < TT - 2)       { asm volatile("s_waitcnt vmcnt(6)" ::: "memory"); }
        else if (T == TT - 2) { asm volatile("s_waitcnt vmcnt(0)" ::: "memory"); }
        SBAR();
    }

    // R2-proven LDS-repack epilogue: two 128-row f32 [128][256] halves.
#pragma unroll
    for (int h2 = 0; h2 < 2; ++h2) {
        if (wr == h2) {
#pragma unroll
            for (int mf = 0; mf < 8; ++mf)
#pragma unroll
                for (int nf = 0; nf < 4; ++nf)
#pragma unroll
                    for (int r = 0; r < 4; ++r) {
                        int rl = mf * 16 + ((l >> 4) << 2) + r;
                        int col = (wc << 6) + nf * 16 + (l & 15);
                        *(float*)(sm + rl * 1024 + col * 4) = acc[mf][nf][r];
                    }
        }
        __syncthreads();
#pragma unroll
        for (int k = 0; k < 16; ++k) {
            int c = t + (k << 9);
            int row = c >> 6, c4 = c & 63;
            f32x4 v = *(const f32x4*)(sm + ((size_t)c << 4));
            int R = brow0 + (h2 << 7) + row;
            int col0 = bcol + (c4 << 2);
            f32x4 bb = *(const f32x4*)(bias + col0);
            f32x4 x0 = *(const f32x4*)(resid + (size_t)R * 512 + col0);
            f32x4 x1 = *(const f32x4*)(resid + (size_t)rolled_row(R) * 512 + col0);
            v = v + bb + x0 + x1;
            *(f32x4*)(outF + (size_t)R * N + col0) = v;
        }
        __syncthreads();
    }
}

// ---------------------------------------------------------------------------
extern "C" void kernel_launch(void* const* d_in, const int* in_sizes, int n_in,
                              void* d_out, int out_size, void* d_ws, size_t ws_size,
                              hipStream_t stream) {
    const float* in = (const float*)d_in[0];
    const float* ln_g = (const float*)d_in[1];
    const float* ln_b = (const float*)d_in[2];
    const float* W1 = (const float*)d_in[3];
    const float* b1 = (const float*)d_in[4];
    const float* W2 = (const float*)d_in[5];
    const float* b2 = (const float*)d_in[6];
    float* out = (float*)d_out;

    char* ws = (char*)d_ws;
    ushort* normed = (ushort*)ws;                                  // 32 MB
    ushort* hbuf   = (ushort*)(ws + (size_t)32 * 1024 * 1024);     // 128 MB (k-permuted)
    ushort* W1T    = (ushort*)(ws + (size_t)160 * 1024 * 1024);    // 2 MB [2048][512]
    ushort* W2T    = (ushort*)(ws + (size_t)162 * 1024 * 1024);    // 2 MB [512][2048] k-permuted

    const int M = 32768;
    const int C = 512, C4 = 2048;

    ln_kernel<<<M, 128, 0, stream>>>(in, ln_g, ln_b, normed);
    transpose_cast<0><<<dim3(C4 / 32, C / 32), dim3(32, 8), 0, stream>>>(W1, W1T, C, C4);
    transpose_cast<1><<<dim3(C / 32, C4 / 32), dim3(32, 8), 0, stream>>>(W2, W2T, C4, C);

    // G1: [32768,512]x[512,2048] -> gelu -> bf16 h (k-permuted), 4096 blocks
    mlp_gemm1<<<dim3(4096), 256, 0, stream>>>(normed, W1T, b1, hbuf);
    // G2: [32768,2048]x[2048,512] + bias + x -> out, persistent 8-phase
    mlp_gemm2<<<dim3(256), 512, 0, stream>>>(hbuf, W2T, b2, in, out);
}

// Round 8
// 213.193 us; speedup vs baseline: 1.7679x; 1.0218x over previous
//
#include <hip/hip_runtime.h>
#include <hip/hip_bf16.h>
#include <cstdint>
#include <cstddef>

// ---------------------------------------------------------------------------
// SwinWindowTransformLayer: roll+add -> LayerNorm -> MLP(GELU) -> +x
// Round 8: G1 = 128x128 tile, BK=64 (half the barriers), correctly-derived
// XOR bank swizzle (chunk ^= row&7 at 128B row stride; pre-swizzled global
// source + swizzled ds_read). G2/LN/transposes frozen from R7.
// ---------------------------------------------------------------------------

typedef short bf16x8 __attribute__((ext_vector_type(8)));
typedef float f32x4 __attribute__((ext_vector_type(4)));

#define GLOBAL_AS(p) ((__attribute__((address_space(1))) void*)(uintptr_t)(p))
#define LDS_AS(p)    ((__attribute__((address_space(3))) void*)(p))

static __device__ __forceinline__ ushort f2bf(float f) {
    uint32_t u = __float_as_uint(f);
    uint32_t r = (u + 0x7FFFu + ((u >> 16) & 1u)) >> 16;
    return (ushort)r;
}

// exact rewrite of tanh-gelu: 0.5v(1+tanh(u)) == v*sigmoid(2u)
static __device__ __forceinline__ float gelu_s(float v) {
    float v2 = v * v;
    float m = fmaf(0.07135481283f, v2, 1.5957691216f);
    float e = __expf(-v * m);
    return v * __builtin_amdgcn_rcpf(1.0f + e);
}

// roll by (-4,-4) on a 64x64 grid
static __device__ __forceinline__ int rolled_row(int row) {
    int b = row >> 12, n = row & 4095;
    int h = n >> 6, wv = n & 63;
    int n2 = (((h + 4) & 63) << 6) | ((wv + 4) & 63);
    return (b << 12) | n2;
}

#define SBAR() do { __builtin_amdgcn_sched_barrier(0); \
                    __builtin_amdgcn_s_barrier(); \
                    __builtin_amdgcn_sched_barrier(0); } while (0)

// ---------------------------------------------------------------------------
__global__ __launch_bounds__(128)
void ln_kernel(const float* __restrict__ in, const float* __restrict__ gamma,
               const float* __restrict__ beta, ushort* __restrict__ normed) {
    const int row = blockIdx.x;
    const int t = threadIdx.x;
    const int row2 = rolled_row(row);

    const float4* p0 = (const float4*)(in + (size_t)row * 512);
    const float4* p1 = (const float4*)(in + (size_t)row2 * 512);
    float4 a = p0[t], c = p1[t];
    float x0 = a.x + c.x, x1 = a.y + c.y, x2 = a.z + c.z, x3 = a.w + c.w;

    float s = x0 + x1 + x2 + x3;
    float sq = x0 * x0 + x1 * x1 + x2 * x2 + x3 * x3;
#pragma unroll
    for (int o = 32; o > 0; o >>= 1) {
        s += __shfl_xor(s, o);
        sq += __shfl_xor(sq, o);
    }
    __shared__ float red[4];
    if ((t & 63) == 0) { red[(t >> 6) * 2] = s; red[(t >> 6) * 2 + 1] = sq; }
    __syncthreads();
    s = red[0] + red[2];
    sq = red[1] + red[3];
    float mu = s * (1.0f / 512.0f);
    float var = sq * (1.0f / 512.0f) - mu * mu;
    float rs = rsqrtf(var + 1e-6f);

    float4 g = ((const float4*)gamma)[t];
    float4 be = ((const float4*)beta)[t];
    ushort4 o4;
    o4.x = f2bf((x0 - mu) * rs * g.x + be.x);
    o4.y = f2bf((x1 - mu) * rs * g.y + be.y);
    o4.z = f2bf((x2 - mu) * rs * g.z + be.z);
    o4.w = f2bf((x3 - mu) * rs * g.w + be.w);
    ((ushort4*)(normed + (size_t)row * 512))[t] = o4;
}

// ---------------------------------------------------------------------------
// transpose + cast fp32 [R][Ccols] -> bf16 [Ccols][R].
// PERM=1: permute k (within 64-blocks: nf*16+c -> c*4+nf) to match the
// permuted hbuf layout written by mlp_gemm1's epilogue.
// ---------------------------------------------------------------------------
template <int PERM>
__global__ __launch_bounds__(256)
void transpose_cast(const float* __restrict__ src, ushort* __restrict__ dst,
                    int R, int Ccols) {
    __shared__ float tile[32][33];
    const int bx = blockIdx.x * 32;
    const int by = blockIdx.y * 32;
    const int tx = threadIdx.x, ty = threadIdx.y;
#pragma unroll
    for (int i = 0; i < 32; i += 8)
        tile[ty + i][tx] = src[(size_t)(by + ty + i) * Ccols + bx + tx];
    __syncthreads();
    int k = by + tx;
    int kd = PERM ? ((k & ~63) | ((k & 15) << 2) | ((k >> 4) & 3)) : k;
#pragma unroll
    for (int i = 0; i < 32; i += 8)
        dst[(size_t)(bx + ty + i) * R + kd] = f2bf(tile[tx][ty + i]);
}

// ---------------------------------------------------------------------------
// G1: h = bf16(gelu(normed @ W1 + b1)), k-permuted packed stores.
// 128x128 tile, BK=64 (8 K-iters), 256 thr (4 waves 2x2), 2-barrier K-loop,
// 2 k-substeps (32 MFMA) per staged tile. Bank swizzle: row stride 128B;
// stored chunk position p = c ^ (row&7); staging source pre-swizzled,
// LDS dest linear (global_load_lds), ds_read applies the same involution.
// XCD row-panel-major block ordering (A-panel L2-hot).
// ---------------------------------------------------------------------------
__global__ __launch_bounds__(256)
void mlp_gemm1(const ushort* __restrict__ A, const ushort* __restrict__ Bt,
               const float* __restrict__ bias, ushort* __restrict__ outH) {
    constexpr int K = 512, N = 2048, BK = 64;
    __shared__ ushort Asm[128 * BK];   // 16 KB
    __shared__ ushort Bsm[128 * BK];   // 16 KB

    const int t = threadIdx.x;
    const int w = t >> 6, l = t & 63;
    const int wr = w >> 1, wc = w & 1;

    // XCD-aware ordering: xcd = bid&7 owns 32 row-panels; the 16 col-blocks
    // of one row-panel are consecutive within the XCD.
    const int bid = blockIdx.x;
    const int xcd = bid & 7, idx = bid >> 3;
    const int brow = ((xcd << 5) + (idx >> 4)) << 7;
    const int bcol = (idx & 15) << 7;

    f32x4 acc[4][4] = {};

    // staging: 8 threads per 128B row; source chunk pre-swizzled c^(row&7)
    const int trow = t >> 3;                              // 0..31 within group
    const int csrc = (((t & 7) ^ ((t >> 3) & 7)) << 3);   // k-elem offset
    const size_t aBase = (size_t)(brow + trow) * K + csrc;
    const size_t bBase = (size_t)(bcol + trow) * K + csrc;
    char* const ldsA = (char*)Asm + w * 1024;   // wave-uniform dest base
    char* const ldsB = (char*)Bsm + w * 1024;

    // fragment reads: row = wseg*64 + i*16 + rA; row&7 == rA&7 (per-lane
    // const). chunk(s) = (s*4 | (l>>4)) ^ (rA&7); bit2 (s) disjoint from c2.
    const int rA = l & 15;
    const int cbase = ((l >> 4) ^ (rA & 7)) << 4;         // byte, bits 4-6
    const int preA = (wr << 13) + (rA << 7) + cbase;      // + i*2048 + s*64(^)
    const int preB = (wc << 13) + (rA << 7) + cbase;

    for (int k0 = 0; k0 < K; k0 += BK) {
#pragma unroll
        for (int i = 0; i < 4; ++i) {
            __builtin_amdgcn_global_load_lds(GLOBAL_AS(A + aBase + (size_t)(i * 32) * K + k0),
                                             LDS_AS(ldsA + i * 4096), 16, 0, 0);
            __builtin_amdgcn_global_load_lds(GLOBAL_AS(Bt + bBase + (size_t)(i * 32) * K + k0),
                                             LDS_AS(ldsB + i * 4096), 16, 0, 0);
        }
        __syncthreads();  // drains vmcnt -> tiles complete

#pragma unroll
        for (int s = 0; s < 2; ++s) {
            const int so = s << 6;   // flips bit 6 == chunk bit 2 (XOR-safe add)
            bf16x8 aF[4], bF[4];
#pragma unroll
            for (int i = 0; i < 4; ++i)
                aF[i] = *(const bf16x8*)((const char*)Asm + ((preA + i * 2048) ^ so));
#pragma unroll
            for (int j = 0; j < 4; ++j)
                bF[j] = *(const bf16x8*)((const char*)Bsm + ((preB + j * 2048) ^ so));
#pragma unroll
            for (int i = 0; i < 4; ++i)
#pragma unroll
                for (int j = 0; j < 4; ++j)
                    acc[i][j] = __builtin_amdgcn_mfma_f32_16x16x32_bf16(aF[i], bF[j], acc[i][j], 0, 0, 0);
        }
        __syncthreads();
    }

    // lean epilogue: gelu_s + packed uint2 stores (k-permuted layout)
    const int cm = (l >> 4) << 2;
    const int cn = l & 15;
    float bvv[4];
#pragma unroll
    for (int j = 0; j < 4; ++j)
        bvv[j] = bias[bcol + wc * 64 + j * 16 + cn];
    const int ecol = bcol + wc * 64 + (cn << 2);
#pragma unroll
    for (int i = 0; i < 4; ++i) {
#pragma unroll
        for (int r = 0; r < 4; ++r) {
            const int row = brow + wr * 64 + i * 16 + cm + r;
            float f0 = gelu_s(acc[i][0][r] + bvv[0]);
            float f1 = gelu_s(acc[i][1][r] + bvv[1]);
            float f2 = gelu_s(acc[i][2][r] + bvv[2]);
            float f3 = gelu_s(acc[i][3][r] + bvv[3]);
            uint32_t lo, hi;
            asm("v_cvt_pk_bf16_f32 %0, %1, %2" : "=v"(lo) : "v"(f0), "v"(f1));
            asm("v_cvt_pk_bf16_f32 %0, %1, %2" : "=v"(hi) : "v"(f2), "v"(f3));
            uint2 pv; pv.x = lo; pv.y = hi;
            *(uint2*)(outH + (size_t)row * N + ecol) = pv;
        }
    }
}

// ---------------------------------------------------------------------------
// G2: out = hbuf @ W2 + b2 + resid[row] + resid[roll(row)].
// Persistent 8-phase 256x256 loop (KT=2048, TT=32) + LDS-repack epilogue.
// Frozen from R7.
// ---------------------------------------------------------------------------
__global__ __launch_bounds__(512, 2)
void mlp_gemm2(const ushort* __restrict__ A, const ushort* __restrict__ Bt,
               const float* __restrict__ bias, const float* __restrict__ resid,
               float* __restrict__ outF) {
    constexpr int KT = 2048, TT = 32, N = 512;
    __shared__ __align__(16) char sm[131072];
    const int t = threadIdx.x;
    const int w = t >> 6, l = t & 63;
    const int wr = w >> 2, wc = w & 3;

    const int nwg = gridDim.x;
    const int bid = blockIdx.x;
    const int swz = (bid & 7) * (nwg >> 3) + (bid >> 3);
    const int cb = swz & 1;
    const int rgrp = swz >> 1;
    const int brow0 = rgrp * 256;
    const int bcol = cb << 8;

    const int kksw = (((t & 3) ^ ((t >> 4) & 3)) << 3);
    const size_t aTh = (size_t)(t >> 2) * KT + kksw;
    const size_t bTh = (size_t)(bcol + (t >> 2)) * KT + kksw;
    const ushort* const aPanel = A + (size_t)brow0 * KT;
    char* const dA = (char*)sm + (w << 10);
    char* const dB = dA + 65536;

    const int xorv = ((l >> 2) & 3) << 4;
    const int preA = ((((wr << 7) + (l & 15)) << 6) + ((l >> 4) << 4)) ^ xorv;
    const int preB = 65536 + (((((wc << 6) + (l & 15)) << 6) + ((l >> 4) << 4)) ^ xorv);

    f32x4 acc[8][4] = {};
    bf16x8 aF[4], bF[4];

    auto issueA = [&](int T, int kh) {
        const int slot = ((T & 1) << 1) | kh;
        const ushort* s = aPanel + aTh + T * 64 + kh * 32;
        char* d = dA + (slot << 14);
        __builtin_amdgcn_global_load_lds(GLOBAL_AS(s), LDS_AS(d), 16, 0, 0);
        __builtin_amdgcn_global_load_lds(GLOBAL_AS(s + (size_t)128 * KT), LDS_AS(d + 8192), 16, 0, 0);
    };
    auto issueB = [&](int T, int kh) {
        const int slot = ((T & 1) << 1) | kh;
        const ushort* s = Bt + bTh + T * 64 + kh * 32;
        char* d = dB + (slot << 14);
        __builtin_amdgcn_global_load_lds(GLOBAL_AS(s), LDS_AS(d), 16, 0, 0);
        __builtin_amdgcn_global_load_lds(GLOBAL_AS(s + (size_t)128 * KT), LDS_AS(d + 8192), 16, 0, 0);
    };
    auto rdA = [&](int slot, int mb) {
        const char* p = (const char*)sm + (slot << 14) + preA + (mb << 12);
        aF[0] = *(const bf16x8*)(p);
        aF[1] = *(const bf16x8*)(p + 1024);
        aF[2] = *(const bf16x8*)(p + 2048);
        aF[3] = *(const bf16x8*)(p + 3072);
    };
    auto rdB = [&](int slot) {
        const char* p = (const char*)sm + (slot << 14) + preB;
        bF[0] = *(const bf16x8*)(p);
        bF[1] = *(const bf16x8*)(p + 1024);
        bF[2] = *(const bf16x8*)(p + 2048);
        bF[3] = *(const bf16x8*)(p + 3072);
    };
    auto mfma16 = [&](int mb) {
        __builtin_amdgcn_s_setprio(1);
#pragma unroll
        for (int mf = 0; mf < 4; ++mf)
#pragma unroll
            for (int nf = 0; nf < 4; ++nf)
                acc[mb * 4 + mf][nf] = __builtin_amdgcn_mfma_f32_16x16x32_bf16(
                    aF[mf], bF[nf], acc[mb * 4 + mf][nf], 0, 0, 0);
        __builtin_amdgcn_s_setprio(0);
    };

    issueA(0, 0); issueB(0, 0);
    issueA(0, 1); issueB(0, 1);
    issueA(1, 0); issueB(1, 0);
    issueA(1, 1);
    __builtin_amdgcn_sched_barrier(0);
    asm volatile("s_waitcnt vmcnt(6)" ::: "memory");
    SBAR();

#pragma unroll 1
    for (int T = 0; T < TT; ++T) {
        const int s0 = (T & 1) << 1;
        rdA(s0, 0); rdB(s0);
        SBAR();
        if (T + 1 < TT) issueB(T + 1, 1);
        mfma16(0);
        SBAR();
        rdA(s0, 1);
        SBAR();
        if (T + 2 < TT) issueA(T + 2, 0);
        mfma16(1);
        SBAR();
        rdA(s0 + 1, 0); rdB(s0 + 1);
        SBAR();
        if (T + 2 < TT) issueB(T + 2, 0);
        mfma16(0);
        SBAR();
        rdA(s0 + 1, 1);
        SBAR();
        if (T + 2 < TT) issueA(T + 2, 1);
        mfma16(1);
        __builtin_amdgcn_sched_barrier(0);
        if (T < TT - 2)       { asm volatile("s_waitcnt vmcnt(6)" ::: "memory"); }
        else if (T == TT - 2) { asm volatile("s_waitcnt vmcnt(0)" ::: "memory"); }
        SBAR();
    }

    // LDS-repack epilogue: two 128-row f32 [128][256] halves.
#pragma unroll
    for (int h2 = 0; h2 < 2; ++h2) {
        if (wr == h2) {
#pragma unroll
            for (int mf = 0; mf < 8; ++mf)
#pragma unroll
                for (int nf = 0; nf < 4; ++nf)
#pragma unroll
                    for (int r = 0; r < 4; ++r) {
                        int rl = mf * 16 + ((l >> 4) << 2) + r;
                        int col = (wc << 6) + nf * 16 + (l & 15);
                        *(float*)(sm + rl * 1024 + col * 4) = acc[mf][nf][r];
                    }
        }
        __syncthreads();
#pragma unroll
        for (int k = 0; k < 16; ++k) {
            int c = t + (k << 9);
            int row = c >> 6, c4 = c & 63;
            f32x4 v = *(const f32x4*)(sm + ((size_t)c << 4));
            int R = brow0 + (h2 << 7) + row;
            int col0 = bcol + (c4 << 2);
            f32x4 bb = *(const f32x4*)(bias + col0);
            f32x4 x0 = *(const f32x4*)(resid + (size_t)R * 512 + col0);
            f32x4 x1 = *(const f32x4*)(resid + (size_t)rolled_row(R) * 512 + col0);
            v = v + bb + x0 + x1;
            *(f32x4*)(outF + (size_t)R * N + col0) = v;
        }
        __syncthreads();
    }
}

// ---------------------------------------------------------------------------
extern "C" void kernel_launch(void* const* d_in, const int* in_sizes, int n_in,
                              void* d_out, int out_size, void* d_ws, size_t ws_size,
                              hipStream_t stream) {
    const float* in = (const float*)d_in[0];
    const float* ln_g = (const float*)d_in[1];
    const float* ln_b = (const float*)d_in[2];
    const float* W1 = (const float*)d_in[3];
    const float* b1 = (const float*)d_in[4];
    const float* W2 = (const float*)d_in[5];
    const float* b2 = (const float*)d_in[6];
    float* out = (float*)d_out;

    char* ws = (char*)d_ws;
    ushort* normed = (ushort*)ws;                                  // 32 MB
    ushort* hbuf   = (ushort*)(ws + (size_t)32 * 1024 * 1024);     // 128 MB (k-permuted)
    ushort* W1T    = (ushort*)(ws + (size_t)160 * 1024 * 1024);    // 2 MB [2048][512]
    ushort* W2T    = (ushort*)(ws + (size_t)162 * 1024 * 1024);    // 2 MB [512][2048] k-permuted

    const int M = 32768;
    const int C = 512, C4 = 2048;

    ln_kernel<<<M, 128, 0, stream>>>(in, ln_g, ln_b, normed);
    transpose_cast<0><<<dim3(C4 / 32, C / 32), dim3(32, 8), 0, stream>>>(W1, W1T, C, C4);
    transpose_cast<1><<<dim3(C / 32, C4 / 32), dim3(32, 8), 0, stream>>>(W2, W2T, C4, C);

    // G1: [32768,512]x[512,2048] -> gelu -> bf16 h (k-permuted), 4096 blocks
    mlp_gemm1<<<dim3(4096), 256, 0, stream>>>(normed, W1T, b1, hbuf);
    // G2: [32768,2048]x[2048,512] + bias + x -> out, persistent 8-phase
    mlp_gemm2<<<dim3(256), 512, 0, stream>>>(hbuf, W2T, b2, in, out);
}